// Round 1
// baseline (4787.520 us; speedup 1.0000x reference)
//
#include <hip/hip_runtime.h>
#include <math.h>

// Problem constants
#define TSTEPS 19   // T-1 decode steps
#define NB 64       // batch
#define NS 64       // src len
#define NT 20       // tgt len
#define NH 512      // hidden
#define NE 256      // emb dim
#define NV 32000    // vocab

// ---------------------------------------------------------------------------
// Generic fp32 linear: C[M,N] = act(A[M,K] @ W[N,K]^T + bias)
// BM=64, BN=128, BK=16; 256 threads; each thread computes 4x8.
// Requires M%64==0 (grid.y=M/64), N%128==0 (grid.x=N/128), K%16==0,
// and 16B-aligned rows (lda/ldw/ldc %4==0).
// ---------------------------------------------------------------------------
__global__ __launch_bounds__(256) void linear_kernel(
    const float* __restrict__ A, int lda,
    const float* __restrict__ W, int ldw,
    const float* __restrict__ bias,
    float* __restrict__ C, int ldc,
    int K, int act)
{
  __shared__ float As[16][68];    // +4 pad: staging writes 2-way (free)
  __shared__ float Ws[16][132];
  const int tid = threadIdx.x;
  const int m0 = blockIdx.y * 64;
  const int n0 = blockIdx.x * 128;
  const int lr = tid >> 2;          // 0..63 tile row for staging
  const int lc = (tid & 3) << 2;    // 0,4,8,12 k-offset for staging
  const int tm = tid & 15;          // a-frag: 16 addrs x4 lanes -> 2-way (free)
  const int tn = tid >> 4;          // w-frag: 4 addrs broadcast (free)

  float acc[4][8];
#pragma unroll
  for (int i = 0; i < 4; ++i)
#pragma unroll
    for (int j = 0; j < 8; ++j) acc[i][j] = 0.f;

  const float* Ar  = A + (size_t)(m0 + lr) * lda + lc;
  const float* Wr0 = W + (size_t)(n0 + lr) * ldw + lc;
  const float* Wr1 = W + (size_t)(n0 + 64 + lr) * ldw + lc;

  for (int kk = 0; kk < K; kk += 16) {
    float4 av = *(const float4*)(Ar + kk);
    float4 w0 = *(const float4*)(Wr0 + kk);
    float4 w1 = *(const float4*)(Wr1 + kk);
    As[lc+0][lr] = av.x; As[lc+1][lr] = av.y; As[lc+2][lr] = av.z; As[lc+3][lr] = av.w;
    Ws[lc+0][lr] = w0.x; Ws[lc+1][lr] = w0.y; Ws[lc+2][lr] = w0.z; Ws[lc+3][lr] = w0.w;
    Ws[lc+0][64+lr] = w1.x; Ws[lc+1][64+lr] = w1.y; Ws[lc+2][64+lr] = w1.z; Ws[lc+3][64+lr] = w1.w;
    __syncthreads();
#pragma unroll
    for (int k = 0; k < 16; ++k) {
      float4 a4 = *(const float4*)&As[k][tm * 4];
      float4 b4 = *(const float4*)&Ws[k][tn * 8];
      float4 b5 = *(const float4*)&Ws[k][tn * 8 + 4];
      float a[4] = {a4.x, a4.y, a4.z, a4.w};
      float b[8] = {b4.x, b4.y, b4.z, b4.w, b5.x, b5.y, b5.z, b5.w};
#pragma unroll
      for (int i = 0; i < 4; ++i)
#pragma unroll
        for (int j = 0; j < 8; ++j)
          acc[i][j] = fmaf(a[i], b[j], acc[i][j]);
    }
    __syncthreads();
  }

#pragma unroll
  for (int i = 0; i < 4; ++i) {
    int m = m0 + tm * 4 + i;
    float* crow = C + (size_t)m * ldc + n0 + tn * 8;
    float vv[8];
#pragma unroll
    for (int j = 0; j < 8; ++j) {
      float v = acc[i][j];
      if (bias) v += bias[n0 + tn * 8 + j];
      if (act == 1) v = tanhf(v);
      vv[j] = v;
    }
    *(float4*)(crow)     = make_float4(vv[0], vv[1], vv[2], vv[3]);
    *(float4*)(crow + 4) = make_float4(vv[4], vv[5], vv[6], vv[7]);
  }
}

// ---------------------------------------------------------------------------
// Fused GRU input GEMMs: blockIdx.z==0 -> gi = [emb[tok], attn_prev] @ W_ih^T + b_ih
//                        blockIdx.z==1 -> gh = h_in @ W_hh^T + b_hh
// M=64 (one m-tile), N=1536 (grid.x=12). Embedding gather folded into A-load.
// ---------------------------------------------------------------------------
__global__ __launch_bounds__(256) void gru_gemm_kernel(
    const float* __restrict__ emb, const int* __restrict__ tgt, int t,
    const float* __restrict__ attn_prev, const float* __restrict__ h_in,
    const float* __restrict__ W_ih, const float* __restrict__ b_ih,
    const float* __restrict__ W_hh, const float* __restrict__ b_hh,
    float* __restrict__ gi, float* __restrict__ gh)
{
  __shared__ float As[16][68];
  __shared__ float Ws[16][132];
  const int z = blockIdx.z;
  const float* W  = z ? W_hh : W_ih;
  const float* bias = z ? b_hh : b_ih;
  float* C = z ? gh : gi;
  const int K = z ? NH : (NE + NH);
  const int ldw = K;

  const int tid = threadIdx.x;
  const int n0 = blockIdx.x * 128;
  const int lr = tid >> 2;
  const int lc = (tid & 3) << 2;
  const int tm = tid & 15;
  const int tn = tid >> 4;

  float acc[4][8];
#pragma unroll
  for (int i = 0; i < 4; ++i)
#pragma unroll
    for (int j = 0; j < 8; ++j) acc[i][j] = 0.f;

  const int tok = (z == 0) ? tgt[lr * NT + t] : 0;
  const float* Wr0 = W + (size_t)(n0 + lr) * ldw + lc;
  const float* Wr1 = W + (size_t)(n0 + 64 + lr) * ldw + lc;

  for (int kk = 0; kk < K; kk += 16) {
    float4 av;
    if (z == 0) {
      int c = kk + lc;
      if (c < NE) av = *(const float4*)(emb + (size_t)tok * NE + c);
      else        av = *(const float4*)(attn_prev + lr * NH + (c - NE));
    } else {
      av = *(const float4*)(h_in + lr * NH + kk + lc);
    }
    float4 w0 = *(const float4*)(Wr0 + kk);
    float4 w1 = *(const float4*)(Wr1 + kk);
    As[lc+0][lr] = av.x; As[lc+1][lr] = av.y; As[lc+2][lr] = av.z; As[lc+3][lr] = av.w;
    Ws[lc+0][lr] = w0.x; Ws[lc+1][lr] = w0.y; Ws[lc+2][lr] = w0.z; Ws[lc+3][lr] = w0.w;
    Ws[lc+0][64+lr] = w1.x; Ws[lc+1][64+lr] = w1.y; Ws[lc+2][64+lr] = w1.z; Ws[lc+3][64+lr] = w1.w;
    __syncthreads();
#pragma unroll
    for (int k = 0; k < 16; ++k) {
      float4 a4 = *(const float4*)&As[k][tm * 4];
      float4 b4 = *(const float4*)&Ws[k][tn * 8];
      float4 b5 = *(const float4*)&Ws[k][tn * 8 + 4];
      float a[4] = {a4.x, a4.y, a4.z, a4.w};
      float b[8] = {b4.x, b4.y, b4.z, b4.w, b5.x, b5.y, b5.z, b5.w};
#pragma unroll
      for (int i = 0; i < 4; ++i)
#pragma unroll
        for (int j = 0; j < 8; ++j)
          acc[i][j] = fmaf(a[i], b[j], acc[i][j]);
    }
    __syncthreads();
  }

#pragma unroll
  for (int i = 0; i < 4; ++i) {
    int m = tm * 4 + i;
    float* crow = C + (size_t)m * 1536 + n0 + tn * 8;
    float vv[8];
#pragma unroll
    for (int j = 0; j < 8; ++j) vv[j] = acc[i][j] + bias[n0 + tn * 8 + j];
    *(float4*)(crow)     = make_float4(vv[0], vv[1], vv[2], vv[3]);
    *(float4*)(crow + 4) = make_float4(vv[4], vv[5], vv[6], vv[7]);
  }
}

// ---------------------------------------------------------------------------
// Fused GRU gate + attention (scores, masked softmax, context) per batch row.
// One block per b (64 blocks). Writes h_out (B,H) and hc = [h | ctx] (B,2H).
// ---------------------------------------------------------------------------
__global__ __launch_bounds__(256) void attn_gate_kernel(
    const float* __restrict__ gi, const float* __restrict__ gh,
    const float* __restrict__ h_prev,
    const float* __restrict__ enc_proj,  // (S,B,H): [(s*64+b)*512+g]
    const float* __restrict__ enc_out,   // (S,B,H)
    const int* __restrict__ len_src,
    float* __restrict__ h_out, float* __restrict__ hc)
{
  const int b = blockIdx.x;
  const int tid = threadIdx.x;
  __shared__ float hnew[NH];
  __shared__ float scs[NS];
  __shared__ float aw[NS];

  // GRU gates
  for (int j = tid; j < NH; j += 256) {
    float ir  = gi[b * 1536 + j];
    float iz  = gi[b * 1536 + 512 + j];
    float inn = gi[b * 1536 + 1024 + j];
    float hr  = gh[b * 1536 + j];
    float hz  = gh[b * 1536 + 512 + j];
    float hn  = gh[b * 1536 + 1024 + j];
    float r  = 1.f / (1.f + expf(-(ir + hr)));
    float zg = 1.f / (1.f + expf(-(iz + hz)));
    float n  = tanhf(inn + r * hn);
    float h  = (1.f - zg) * n + zg * h_prev[b * NH + j];
    hnew[j] = h;
    h_out[b * NH + j] = h;
    hc[b * 1024 + j] = h;
  }
  __syncthreads();

  // scores: 4 lanes per s
  {
    int s = tid >> 2, sub = tid & 3;
    const float* ep = enc_proj + ((size_t)s * NB + b) * NH;
    float acc = 0.f;
    for (int g = sub; g < NH; g += 4) acc += hnew[g] * ep[g];
    acc += __shfl_xor(acc, 1);
    acc += __shfl_xor(acc, 2);
    if (sub == 0) scs[s] = acc;
  }
  __syncthreads();

  // masked softmax over S=64 by the first wave
  if (tid < 64) {
    int len = len_src[b];
    float v = (tid < len) ? scs[tid] : -1e9f;
    float m = v;
    for (int off = 32; off >= 1; off >>= 1) m = fmaxf(m, __shfl_xor(m, off));
    float e = expf(v - m);
    float ssum = e;
    for (int off = 32; off >= 1; off >>= 1) ssum += __shfl_xor(ssum, off);
    aw[tid] = e / ssum;
  }
  __syncthreads();

  // ctx
  for (int g = tid; g < NH; g += 256) {
    float c = 0.f;
#pragma unroll 4
    for (int s2 = 0; s2 < NS; ++s2)
      c += aw[s2] * enc_out[((size_t)s2 * NB + b) * NH + g];
    hc[b * 1024 + 512 + g] = c;
  }
}

// ---------------------------------------------------------------------------
// Per-row (1216 rows) log-softmax in place + argmax word.
// Tie-break: lowest index (numpy argmax semantics).
// ---------------------------------------------------------------------------
__global__ __launch_bounds__(256) void row_softmax_kernel(
    float* __restrict__ out, float* __restrict__ words)
{
  const int row = blockIdx.x;
  const int tid = threadIdx.x;
  float* p = out + (size_t)row * NV;
  __shared__ float sval[256];
  __shared__ int   sidx[256];

  float m = -INFINITY; int mi = 0;
  for (int i = tid; i < NV; i += 256) {
    float v = p[i];
    if (v > m) { m = v; mi = i; }
  }
  sval[tid] = m; sidx[tid] = mi;
  __syncthreads();
  for (int off = 128; off >= 1; off >>= 1) {
    if (tid < off) {
      float v2 = sval[tid + off]; int i2 = sidx[tid + off];
      if (v2 > sval[tid] || (v2 == sval[tid] && i2 < sidx[tid])) {
        sval[tid] = v2; sidx[tid] = i2;
      }
    }
    __syncthreads();
  }
  const float M = sval[0];
  const int MI = sidx[0];

  float s = 0.f;
  for (int i = tid; i < NV; i += 256) s += expf(p[i] - M);
  __syncthreads();           // everyone done reading sval[0]
  sval[tid] = s;
  __syncthreads();
  for (int off = 128; off >= 1; off >>= 1) {
    if (tid < off) sval[tid] += sval[tid + off];
    __syncthreads();
  }
  const float lse = M + logf(sval[0]);

  for (int i = tid; i < NV; i += 256) p[i] -= lse;
  if (tid == 0) words[row] = (float)MI;
}

// init: zero attn slot 0, copy h0 = enc_final[0]
__global__ __launch_bounds__(256) void init_kernel(
    float* __restrict__ attn0, float* __restrict__ h0,
    const float* __restrict__ enc_final)
{
  int i = blockIdx.x * 256 + threadIdx.x;
  if (i < NB * NH) {
    attn0[i] = 0.f;
    h0[i] = enc_final[i];
  }
}

extern "C" void kernel_launch(void* const* d_in, const int* in_sizes, int n_in,
                              void* d_out, int out_size, void* d_ws, size_t ws_size,
                              hipStream_t stream) {
  const int*   tgt       = (const int*)d_in[0];
  const int*   len_src   = (const int*)d_in[1];
  const float* enc_final = (const float*)d_in[3];
  const float* enc_out   = (const float*)d_in[4];
  const float* emb       = (const float*)d_in[6];
  const float* W_ih      = (const float*)d_in[7];
  const float* W_hh      = (const float*)d_in[8];
  const float* b_ih      = (const float*)d_in[9];
  const float* b_hh      = (const float*)d_in[10];
  const float* W_attn    = (const float*)d_in[11];
  const float* W_concat  = (const float*)d_in[12];
  const float* b_concat  = (const float*)d_in[13];
  const float* W_out     = (const float*)d_in[14];
  const float* b_out     = (const float*)d_in[15];
  float* out = (float*)d_out;

  // workspace layout (floats); total ~3.08M floats = 12.3 MB
  float* ws = (float*)d_ws;
  float* enc_proj = ws;                        // 4096*512  (S,B,H)
  float* gi       = enc_proj + 4096 * 512;     // 64*1536
  float* gh       = gi + 64 * 1536;            // 64*1536
  float* hbuf0    = gh + 64 * 1536;            // 64*512
  float* hbuf1    = hbuf0 + 64 * 512;          // 64*512
  float* attn_all = hbuf1 + 64 * 512;          // 20*64*512 (slot 0 = zeros)
  float* hc       = attn_all + 20 * 64 * 512;  // 64*1024

  init_kernel<<<128, 256, 0, stream>>>(attn_all, hbuf0, enc_final);

  // enc_proj[s,b,:] = enc_out[s,b,:] @ W_attn^T   (M=4096, N=512, K=512)
  linear_kernel<<<dim3(512 / 128, 4096 / 64), 256, 0, stream>>>(
      enc_out, 512, W_attn, 512, nullptr, enc_proj, 512, 512, 0);

  for (int t = 0; t < TSTEPS; ++t) {
    float* h_in  = (t & 1) ? hbuf1 : hbuf0;
    float* h_out = (t & 1) ? hbuf0 : hbuf1;
    const float* attn_prev = attn_all + (size_t)t * NB * NH;

    gru_gemm_kernel<<<dim3(12, 1, 2), 256, 0, stream>>>(
        emb, tgt, t, attn_prev, h_in, W_ih, b_ih, W_hh, b_hh, gi, gh);

    attn_gate_kernel<<<64, 256, 0, stream>>>(
        gi, gh, h_in, enc_proj, enc_out, len_src, h_out, hc);

    // attn_h[t] = tanh(hc @ W_concat^T + b_concat)  (M=64, N=512, K=1024)
    linear_kernel<<<dim3(4, 1), 256, 0, stream>>>(
        hc, 1024, W_concat, 1024, b_concat,
        attn_all + (size_t)(t + 1) * NB * NH, 512, 1024, 1);
  }

  // logits for all steps at once: (1216 x 512) @ (512 x 32000)
  linear_kernel<<<dim3(NV / 128, (TSTEPS * NB) / 64), 256, 0, stream>>>(
      attn_all + NB * NH, 512, W_out, 512, b_out, out, NV, 512, 0);

  // in-place log-softmax + argmax words
  row_softmax_kernel<<<TSTEPS * NB, 256, 0, stream>>>(
      out, out + (size_t)TSTEPS * NB * NV);
}

// Round 2
// 3858.966 us; speedup vs baseline: 1.2406x; 1.2406x over previous
//
#include <hip/hip_runtime.h>
#include <hip/hip_cooperative_groups.h>
#include <math.h>

namespace cg = cooperative_groups;

// Problem constants
#define TSTEPS 19   // T-1 decode steps
#define NB 64       // batch
#define NS 64       // src len
#define NT 20       // tgt len
#define NH 512      // hidden
#define NE 256      // emb dim
#define NV 32000    // vocab

// ---------------------------------------------------------------------------
// Generic fp32 linear: C[M,N] = A[M,K] @ W[N,K]^T (+bias). BM=64, BN=128,
// BK=16; 256 threads; 4x8 per thread. (used for enc_proj only now)
// ---------------------------------------------------------------------------
__global__ __launch_bounds__(256) void linear_kernel(
    const float* __restrict__ A, int lda,
    const float* __restrict__ W, int ldw,
    const float* __restrict__ bias,
    float* __restrict__ C, int ldc,
    int K, int act)
{
  __shared__ float As[16][68];
  __shared__ float Ws[16][132];
  const int tid = threadIdx.x;
  const int m0 = blockIdx.y * 64;
  const int n0 = blockIdx.x * 128;
  const int lr = tid >> 2;
  const int lc = (tid & 3) << 2;
  const int tm = tid & 15;
  const int tn = tid >> 4;

  float acc[4][8];
#pragma unroll
  for (int i = 0; i < 4; ++i)
#pragma unroll
    for (int j = 0; j < 8; ++j) acc[i][j] = 0.f;

  const float* Ar  = A + (size_t)(m0 + lr) * lda + lc;
  const float* Wr0 = W + (size_t)(n0 + lr) * ldw + lc;
  const float* Wr1 = W + (size_t)(n0 + 64 + lr) * ldw + lc;

  for (int kk = 0; kk < K; kk += 16) {
    float4 av = *(const float4*)(Ar + kk);
    float4 w0 = *(const float4*)(Wr0 + kk);
    float4 w1 = *(const float4*)(Wr1 + kk);
    As[lc+0][lr] = av.x; As[lc+1][lr] = av.y; As[lc+2][lr] = av.z; As[lc+3][lr] = av.w;
    Ws[lc+0][lr] = w0.x; Ws[lc+1][lr] = w0.y; Ws[lc+2][lr] = w0.z; Ws[lc+3][lr] = w0.w;
    Ws[lc+0][64+lr] = w1.x; Ws[lc+1][64+lr] = w1.y; Ws[lc+2][64+lr] = w1.z; Ws[lc+3][64+lr] = w1.w;
    __syncthreads();
#pragma unroll
    for (int k = 0; k < 16; ++k) {
      float4 a4 = *(const float4*)&As[k][tm * 4];
      float4 b4 = *(const float4*)&Ws[k][tn * 8];
      float4 b5 = *(const float4*)&Ws[k][tn * 8 + 4];
      float a[4] = {a4.x, a4.y, a4.z, a4.w};
      float b[8] = {b4.x, b4.y, b4.z, b4.w, b5.x, b5.y, b5.z, b5.w};
#pragma unroll
      for (int i = 0; i < 4; ++i)
#pragma unroll
        for (int j = 0; j < 8; ++j)
          acc[i][j] = fmaf(a[i], b[j], acc[i][j]);
    }
    __syncthreads();
  }

#pragma unroll
  for (int i = 0; i < 4; ++i) {
    int m = m0 + tm * 4 + i;
    float* crow = C + (size_t)m * ldc + n0 + tn * 8;
    float vv[8];
#pragma unroll
    for (int j = 0; j < 8; ++j) {
      float v = acc[i][j];
      if (bias) v += bias[n0 + tn * 8 + j];
      if (act == 1) v = tanhf(v);
      vv[j] = v;
    }
    *(float4*)(crow)     = make_float4(vv[0], vv[1], vv[2], vv[3]);
    *(float4*)(crow + 4) = make_float4(vv[4], vv[5], vv[6], vv[7]);
  }
}

// ---------------------------------------------------------------------------
// gi_emb[t*64+b][:] = emb[tgt[b][t]] @ W_ih[:, :256]^T + b_ih   (1216 x 1536)
// Embedding gather folded into A-load. K=256, ldw=768.
// ---------------------------------------------------------------------------
__global__ __launch_bounds__(256) void emb_linear_kernel(
    const float* __restrict__ emb, const int* __restrict__ tgt,
    const float* __restrict__ W_ih, const float* __restrict__ b_ih,
    float* __restrict__ C)
{
  __shared__ float As[16][68];
  __shared__ float Ws[16][132];
  const int tid = threadIdx.x;
  const int m0 = blockIdx.y * 64;
  const int n0 = blockIdx.x * 128;
  const int lr = tid >> 2;
  const int lc = (tid & 3) << 2;
  const int tm = tid & 15;
  const int tn = tid >> 4;

  float acc[4][8];
#pragma unroll
  for (int i = 0; i < 4; ++i)
#pragma unroll
    for (int j = 0; j < 8; ++j) acc[i][j] = 0.f;

  const int row = m0 + lr;                 // row = t*64 + b
  const int tok = tgt[(row & 63) * NT + (row >> 6)];
  const float* Ar  = emb + (size_t)tok * NE + lc;
  const float* Wr0 = W_ih + (size_t)(n0 + lr) * 768 + lc;
  const float* Wr1 = W_ih + (size_t)(n0 + 64 + lr) * 768 + lc;

  for (int kk = 0; kk < NE; kk += 16) {
    float4 av = *(const float4*)(Ar + kk);
    float4 w0 = *(const float4*)(Wr0 + kk);
    float4 w1 = *(const float4*)(Wr1 + kk);
    As[lc+0][lr] = av.x; As[lc+1][lr] = av.y; As[lc+2][lr] = av.z; As[lc+3][lr] = av.w;
    Ws[lc+0][lr] = w0.x; Ws[lc+1][lr] = w0.y; Ws[lc+2][lr] = w0.z; Ws[lc+3][lr] = w0.w;
    Ws[lc+0][64+lr] = w1.x; Ws[lc+1][64+lr] = w1.y; Ws[lc+2][64+lr] = w1.z; Ws[lc+3][64+lr] = w1.w;
    __syncthreads();
#pragma unroll
    for (int k = 0; k < 16; ++k) {
      float4 a4 = *(const float4*)&As[k][tm * 4];
      float4 b4 = *(const float4*)&Ws[k][tn * 8];
      float4 b5 = *(const float4*)&Ws[k][tn * 8 + 4];
      float a[4] = {a4.x, a4.y, a4.z, a4.w};
      float b[8] = {b4.x, b4.y, b4.z, b4.w, b5.x, b5.y, b5.z, b5.w};
#pragma unroll
      for (int i = 0; i < 4; ++i)
#pragma unroll
        for (int j = 0; j < 8; ++j)
          acc[i][j] = fmaf(a[i], b[j], acc[i][j]);
    }
    __syncthreads();
  }

#pragma unroll
  for (int i = 0; i < 4; ++i) {
    int m = m0 + tm * 4 + i;
    float* crow = C + (size_t)m * 1536 + n0 + tn * 8;
    float vv[8];
#pragma unroll
    for (int j = 0; j < 8; ++j) vv[j] = acc[i][j] + b_ih[n0 + tn * 8 + j];
    *(float4*)(crow)     = make_float4(vv[0], vv[1], vv[2], vv[3]);
    *(float4*)(crow + 4) = make_float4(vv[4], vv[5], vv[6], vv[7]);
  }
}

// ---------------------------------------------------------------------------
// Logits GEMM with XCD-ownership swizzle. C[1216,32000] = A @ W_out^T + b_out.
// Flat grid 8 xcd * 32 nt * 19 mt = 4864 blocks. Each XCD (b&7, assuming
// round-robin dispatch — perf-only heuristic) owns a contiguous 32-n-tile
// slice; within it, m-tile varies fastest so co-resident blocks share the
// same 256KB W-tile in that XCD's L2. Cuts W_out re-fetch from HBM.
// ---------------------------------------------------------------------------
__global__ __launch_bounds__(256) void logits_kernel(
    const float* __restrict__ A, const float* __restrict__ W,
    const float* __restrict__ bias, float* __restrict__ C)
{
  const int bfl = blockIdx.x;
  const int xcd = bfl & 7;
  const int jj = bfl >> 3;
  const int mt = jj % 19;
  const int nt = xcd * 32 + jj / 19;
  if (nt >= 250) return;          // uniform whole-block exit before barriers
  const int m0 = mt * 64;
  const int n0 = nt * 128;

  __shared__ float As[16][68];
  __shared__ float Ws[16][132];
  const int tid = threadIdx.x;
  const int lr = tid >> 2;
  const int lc = (tid & 3) << 2;
  const int tm = tid & 15;
  const int tn = tid >> 4;

  float acc[4][8];
#pragma unroll
  for (int i = 0; i < 4; ++i)
#pragma unroll
    for (int j = 0; j < 8; ++j) acc[i][j] = 0.f;

  const float* Ar  = A + (size_t)(m0 + lr) * NH + lc;
  const float* Wr0 = W + (size_t)(n0 + lr) * NH + lc;
  const float* Wr1 = W + (size_t)(n0 + 64 + lr) * NH + lc;

  for (int kk = 0; kk < NH; kk += 16) {
    float4 av = *(const float4*)(Ar + kk);
    float4 w0 = *(const float4*)(Wr0 + kk);
    float4 w1 = *(const float4*)(Wr1 + kk);
    As[lc+0][lr] = av.x; As[lc+1][lr] = av.y; As[lc+2][lr] = av.z; As[lc+3][lr] = av.w;
    Ws[lc+0][lr] = w0.x; Ws[lc+1][lr] = w0.y; Ws[lc+2][lr] = w0.z; Ws[lc+3][lr] = w0.w;
    Ws[lc+0][64+lr] = w1.x; Ws[lc+1][64+lr] = w1.y; Ws[lc+2][64+lr] = w1.z; Ws[lc+3][64+lr] = w1.w;
    __syncthreads();
#pragma unroll
    for (int k = 0; k < 16; ++k) {
      float4 a4 = *(const float4*)&As[k][tm * 4];
      float4 b4 = *(const float4*)&Ws[k][tn * 8];
      float4 b5 = *(const float4*)&Ws[k][tn * 8 + 4];
      float a[4] = {a4.x, a4.y, a4.z, a4.w};
      float b[8] = {b4.x, b4.y, b4.z, b4.w, b5.x, b5.y, b5.z, b5.w};
#pragma unroll
      for (int i = 0; i < 4; ++i)
#pragma unroll
        for (int j = 0; j < 8; ++j)
          acc[i][j] = fmaf(a[i], b[j], acc[i][j]);
    }
    __syncthreads();
  }

#pragma unroll
  for (int i = 0; i < 4; ++i) {
    int m = m0 + tm * 4 + i;
    float* crow = C + (size_t)m * NV + n0 + tn * 8;
    float vv[8];
#pragma unroll
    for (int j = 0; j < 8; ++j) vv[j] = acc[i][j] + bias[n0 + tn * 8 + j];
    *(float4*)(crow)     = make_float4(vv[0], vv[1], vv[2], vv[3]);
    *(float4*)(crow + 4) = make_float4(vv[4], vv[5], vv[6], vv[7]);
  }
}

// ---------------------------------------------------------------------------
// Cooperative recurrence kernel: all 19 steps, 2 grid.sync() per step.
// Grid 256 blocks x 256 threads.
//   Phase A (blocks 0..191): giA = attn_prev @ W_ih[:,256:]^T  (96 blocks)
//                            ghA = h_prev    @ W_hh^T          (96 blocks)
//     Block tile 64m x 16n, K=512 in chunks of 64; thread = 1m x 4n.
//     As stored [m][k] stride 68 -> b128 reads are bank-uniform (8/bank min).
//   Phase B (blocks 0..63, one per batch row): gates (adding gi_emb[t] and
//     b_hh), h_new, attention scores vs enc_proj, masked softmax, context,
//     concat GEMM (W_concat from L2, hc in LDS), tanh -> attn_all[t+1].
// ---------------------------------------------------------------------------
__global__ __launch_bounds__(256) void recur_kernel(
    const float* __restrict__ gi_emb, float* __restrict__ giA,
    float* __restrict__ ghA, float* __restrict__ hbuf,
    float* __restrict__ attn_all,
    const float* __restrict__ enc_proj, const float* __restrict__ enc_out,
    const int* __restrict__ len_src,
    const float* __restrict__ W_ih, const float* __restrict__ W_hh,
    const float* __restrict__ b_hh, const float* __restrict__ W_concat,
    const float* __restrict__ b_concat)
{
  cg::grid_group grid = cg::this_grid();
  const int blk = blockIdx.x;
  const int tid = threadIdx.x;

  __shared__ float As[64][68];   // A chunk, [m][k], stride 68 (16B-aligned rows)
  __shared__ float Ws[16][68];   // W chunk, [n][k]
  __shared__ float hcL[2 * NH];  // [h_new | ctx]
  __shared__ float scs[NS];
  __shared__ float aw[NS];

  // phase-A per-thread indices
  const int am  = tid >> 2;          // staging: A row
  const int ac4 = (tid & 3) << 4;    // staging: A col base (x16 floats)
  const int wn  = tid >> 4;          // staging: W row
  const int wc  = (tid & 15) << 2;   // staging: W col base (x4 floats)
  const int m   = tid & 63;          // compute: output row
  const int nq  = tid >> 6;          // compute: output col quad

  for (int t = 0; t < TSTEPS; ++t) {
    const float* attn_prev = attn_all + (size_t)t * NB * NH;
    const float* h_prev = hbuf + (size_t)(t & 1) * NB * NH;
    float* h_next = hbuf + (size_t)((t & 1) ^ 1) * NB * NH;

    // ---------------- Phase A ----------------
    if (blk < 192) {
      const int half = blk / 96;       // 0: gi-part, 1: gh-part
      const int n0 = (blk % 96) * 16;
      const float* Asrc = half ? h_prev : attn_prev;
      const float* Wsrc = half ? W_hh : (W_ih + NE);
      const int ldw = half ? NH : (NE + NH);
      float* Cdst = half ? ghA : giA;

      float acc[4] = {0.f, 0.f, 0.f, 0.f};
      for (int k0 = 0; k0 < NH; k0 += 64) {
#pragma unroll
        for (int u = 0; u < 4; ++u) {
          float4 av = *(const float4*)(Asrc + (size_t)am * NH + k0 + ac4 + 4 * u);
          *(float4*)&As[am][ac4 + 4 * u] = av;
        }
        {
          float4 wv = *(const float4*)(Wsrc + (size_t)(n0 + wn) * ldw + k0 + wc);
          *(float4*)&Ws[wn][wc] = wv;
        }
        __syncthreads();
#pragma unroll
        for (int kc4 = 0; kc4 < 16; ++kc4) {
          float4 a4 = *(const float4*)&As[m][kc4 * 4];
#pragma unroll
          for (int j = 0; j < 4; ++j) {
            float4 w4 = *(const float4*)&Ws[nq * 4 + j][kc4 * 4];
            acc[j] = fmaf(a4.x, w4.x, acc[j]);
            acc[j] = fmaf(a4.y, w4.y, acc[j]);
            acc[j] = fmaf(a4.z, w4.z, acc[j]);
            acc[j] = fmaf(a4.w, w4.w, acc[j]);
          }
        }
        __syncthreads();
      }
      *(float4*)(Cdst + (size_t)m * 1536 + n0 + nq * 4) =
          make_float4(acc[0], acc[1], acc[2], acc[3]);
    }
    grid.sync();

    // ---------------- Phase B (fused gates+attn+concat) ----------------
    if (blk < NB) {
      const int b = blk;
      const float* ge = gi_emb + (size_t)(t * NB + b) * 1536;
      // GRU gates
      for (int j = tid; j < NH; j += 256) {
        float ir  = giA[b * 1536 + j]        + ge[j];
        float iz  = giA[b * 1536 + 512 + j]  + ge[512 + j];
        float inn = giA[b * 1536 + 1024 + j] + ge[1024 + j];
        float hr  = ghA[b * 1536 + j]        + b_hh[j];
        float hz  = ghA[b * 1536 + 512 + j]  + b_hh[512 + j];
        float hn  = ghA[b * 1536 + 1024 + j] + b_hh[1024 + j];
        float r  = 1.f / (1.f + expf(-(ir + hr)));
        float zg = 1.f / (1.f + expf(-(iz + hz)));
        float n  = tanhf(inn + r * hn);
        float h  = (1.f - zg) * n + zg * h_prev[b * NH + j];
        hcL[j] = h;
        h_next[b * NH + j] = h;
      }
      __syncthreads();
      // attention scores: 4 lanes per s
      {
        int s = tid >> 2, sub = tid & 3;
        const float* ep = enc_proj + ((size_t)s * NB + b) * NH;
        float acc = 0.f;
        for (int gg = sub; gg < NH; gg += 4) acc += hcL[gg] * ep[gg];
        acc += __shfl_xor(acc, 1);
        acc += __shfl_xor(acc, 2);
        if (sub == 0) scs[s] = acc;
      }
      __syncthreads();
      // masked softmax by wave 0
      if (tid < 64) {
        int len = len_src[b];
        float v = (tid < len) ? scs[tid] : -1e9f;
        float mm = v;
        for (int off = 32; off >= 1; off >>= 1) mm = fmaxf(mm, __shfl_xor(mm, off));
        float e = expf(v - mm);
        float ssum = e;
        for (int off = 32; off >= 1; off >>= 1) ssum += __shfl_xor(ssum, off);
        aw[tid] = e / ssum;
      }
      __syncthreads();
      // context
      for (int gg = tid; gg < NH; gg += 256) {
        float c = 0.f;
#pragma unroll 4
        for (int s2 = 0; s2 < NS; ++s2)
          c += aw[s2] * enc_out[((size_t)s2 * NB + b) * NH + gg];
        hcL[NH + gg] = c;
      }
      __syncthreads();
      // concat GEMM: attn_h[t+1][b][n] = tanh(W_concat[n,:] . hcL + b_concat[n])
      float* adst = attn_all + (size_t)(t + 1) * NB * NH + (size_t)b * NH;
#pragma unroll
      for (int h2 = 0; h2 < 2; ++h2) {
        int n = tid + h2 * 256;
        const float* wr = W_concat + (size_t)n * (2 * NH);
        float acc = 0.f;
        for (int k = 0; k < 2 * NH; k += 4) {
          float4 w4 = *(const float4*)(wr + k);
          acc = fmaf(w4.x, hcL[k],     acc);
          acc = fmaf(w4.y, hcL[k + 1], acc);
          acc = fmaf(w4.z, hcL[k + 2], acc);
          acc = fmaf(w4.w, hcL[k + 3], acc);
        }
        adst[n] = tanhf(acc + b_concat[n]);
      }
    }
    grid.sync();
  }
}

// ---------------------------------------------------------------------------
// Online single-pass log-softmax + argmax per row (1216 rows).
// Pass 1: online (max, argmax, sum-exp). Pass 2: subtract lse.
// ---------------------------------------------------------------------------
__global__ __launch_bounds__(256) void row_softmax_kernel(
    float* __restrict__ out, float* __restrict__ words)
{
  const int row = blockIdx.x;
  const int tid = threadIdx.x;
  float* p = out + (size_t)row * NV;
  __shared__ float sm[256];
  __shared__ int   si[256];
  __shared__ float ss[256];

  float mv = -INFINITY; int mi = 0; float s = 0.f;
  for (int i = tid; i < NV; i += 256) {
    float v = p[i];
    if (v > mv) {
      s = s * expf(mv - v) + 1.f;   // expf(-inf)=0 handles first element
      mv = v; mi = i;
    } else {
      s += expf(v - mv);
    }
  }
  sm[tid] = mv; si[tid] = mi; ss[tid] = s;
  __syncthreads();
  for (int off = 128; off >= 1; off >>= 1) {
    if (tid < off) {
      float m1 = sm[tid], m2 = sm[tid + off];
      float s1 = ss[tid], s2 = ss[tid + off];
      int   i1 = si[tid], i2 = si[tid + off];
      float M = fmaxf(m1, m2);
      ss[tid] = s1 * expf(m1 - M) + s2 * expf(m2 - M);
      if (m2 > m1 || (m2 == m1 && i2 < i1)) { sm[tid] = m2; si[tid] = i2; }
    }
    __syncthreads();
  }
  const float lse = sm[0] + logf(ss[0]);
  for (int i = tid; i < NV; i += 256) p[i] -= lse;
  if (tid == 0) words[row] = (float)si[0];
}

// init: zero attn slot 0, copy h0 = enc_final[0]
__global__ __launch_bounds__(256) void init_kernel(
    float* __restrict__ attn0, float* __restrict__ h0,
    const float* __restrict__ enc_final)
{
  int i = blockIdx.x * 256 + threadIdx.x;
  if (i < NB * NH) {
    attn0[i] = 0.f;
    h0[i] = enc_final[i];
  }
}

extern "C" void kernel_launch(void* const* d_in, const int* in_sizes, int n_in,
                              void* d_out, int out_size, void* d_ws, size_t ws_size,
                              hipStream_t stream) {
  const int*   tgt       = (const int*)d_in[0];
  const int*   len_src   = (const int*)d_in[1];
  const float* enc_final = (const float*)d_in[3];
  const float* enc_out   = (const float*)d_in[4];
  const float* emb       = (const float*)d_in[6];
  const float* W_ih      = (const float*)d_in[7];
  const float* W_hh      = (const float*)d_in[8];
  const float* b_ih      = (const float*)d_in[9];
  const float* b_hh      = (const float*)d_in[10];
  const float* W_attn    = (const float*)d_in[11];
  const float* W_concat  = (const float*)d_in[12];
  const float* b_concat  = (const float*)d_in[13];
  const float* W_out     = (const float*)d_in[14];
  const float* b_out     = (const float*)d_in[15];
  float* out = (float*)d_out;

  // workspace layout (floats): total ~4.88M floats = 19.5 MB
  float* ws = (float*)d_ws;
  float* enc_proj = ws;                         // 64*64*512   = 2,097,152
  float* gi_emb   = enc_proj + 2097152;         // 1216*1536   = 1,867,776
  float* giA      = gi_emb + 1867776;           // 64*1536
  float* ghA      = giA + 98304;                // 64*1536
  float* hbuf     = ghA + 98304;                // 2*64*512
  float* attn_all = hbuf + 65536;               // 20*64*512

  init_kernel<<<128, 256, 0, stream>>>(attn_all, hbuf, enc_final);

  // enc_proj = enc_out @ W_attn^T   (M=4096, N=512, K=512)
  linear_kernel<<<dim3(4, 64), 256, 0, stream>>>(
      enc_out, 512, W_attn, 512, nullptr, enc_proj, 512, 512, 0);

  // gi_emb = emb[tgt] @ W_ih[:, :256]^T + b_ih  (M=1216, N=1536, K=256)
  emb_linear_kernel<<<dim3(12, 19), 256, 0, stream>>>(
      emb, tgt, W_ih, b_ih, gi_emb);

  // whole recurrence: one cooperative kernel
  void* kargs[] = {
    (void*)&gi_emb, (void*)&giA, (void*)&ghA, (void*)&hbuf, (void*)&attn_all,
    (void*)&enc_proj, (void*)&enc_out, (void*)&len_src,
    (void*)&W_ih, (void*)&W_hh, (void*)&b_hh, (void*)&W_concat, (void*)&b_concat
  };
  hipLaunchCooperativeKernel((const void*)recur_kernel, dim3(256), dim3(256),
                             kargs, 0, stream);

  // logits for all steps: (1216 x 512) @ (512 x 32000), XCD-swizzled
  logits_kernel<<<4864, 256, 0, stream>>>(
      attn_all + NB * NH, W_out, b_out, out);

  // online log-softmax + argmax words
  row_softmax_kernel<<<TSTEPS * NB, 256, 0, stream>>>(
      out, out + (size_t)TSTEPS * NB * NV);
}